// Round 4
// baseline (592.268 us; speedup 1.0000x reference)
//
#include <hip/hip_runtime.h>
#include <hip/hip_bf16.h>
#include <math.h>

typedef __attribute__((ext_vector_type(8))) short short8;
typedef __attribute__((ext_vector_type(4))) short short4v;
typedef __attribute__((ext_vector_type(4))) float f32x4;
typedef __attribute__((ext_vector_type(2))) unsigned int u32x2;

#define GAS __attribute__((address_space(1)))
#define LAS __attribute__((address_space(3)))

__device__ __forceinline__ LAS void* to_lds(void* p) {
    return (LAS void*)(unsigned)(uintptr_t)p;
}

constexpr int Bc = 4, Tc = 2048, Dc = 1024, Nheads = 16, Hc = 64, Fc = 4096;
constexpr int Mrows = Bc * Tc;          // 8192
constexpr float LNEPS = 1e-6f;

__device__ __forceinline__ float gelu_exact(float x) {
    return 0.5f * x * (1.0f + erff(x * 0.70710678118654752440f));
}

// ---------- fp32 [K,N] -> bf16 [N,K] transpose+convert ----------
__global__ __launch_bounds__(256) void transpose_cvt(const float* __restrict__ src,
                                                     __hip_bfloat16* __restrict__ dst,
                                                     int K, int N) {
    __shared__ float tile[32][33];
    const int n0 = blockIdx.x * 32, k0 = blockIdx.y * 32;
    const int tx = threadIdx.x & 31, ty = threadIdx.x >> 5;   // 32 x 8
    #pragma unroll
    for (int i = 0; i < 32; i += 8)
        tile[ty + i][tx] = src[(size_t)(k0 + ty + i) * N + (n0 + tx)];
    __syncthreads();
    #pragma unroll
    for (int i = 0; i < 32; i += 8)
        dst[(size_t)(n0 + ty + i) * K + (k0 + tx)] = __float2bfloat16(tile[tx][ty + i]);
}

// ---------- V pre-transpose: qkv V-slice [t][h] -> vT[b][n][h][t] (bf16) ----------
__global__ __launch_bounds__(256) void transpose_v(const __hip_bfloat16* __restrict__ qkv,
                                                   __hip_bfloat16* __restrict__ vT) {
    __shared__ short tile[32][33];
    const int t0 = blockIdx.x * 32, h0 = blockIdx.y * 32, bn = blockIdx.z;
    const int b = bn >> 4, n = bn & 15;
    const short* src = (const short*)qkv + (size_t)b * Tc * 3072 + 2048 + n * 64;
    short* dst = (short*)vT + (size_t)bn * 64 * Tc;
    const int tx = threadIdx.x & 31, ty = threadIdx.x >> 5;
    #pragma unroll
    for (int i = 0; i < 32; i += 8)
        tile[ty + i][tx] = src[(size_t)(t0 + ty + i) * 3072 + h0 + tx];
    __syncthreads();
    #pragma unroll
    for (int i = 0; i < 32; i += 8)
        dst[(size_t)(h0 + ty + i) * Tc + t0 + tx] = tile[tx][ty + i];
}

// ---------- concat bq,bk,bv -> [3072] ----------
__global__ void concat_bias(const float* __restrict__ bq, const float* __restrict__ bk,
                            const float* __restrict__ bv, float* __restrict__ dst) {
    int i = blockIdx.x * 256 + threadIdx.x;   // 3072 total
    float v = (i < 1024) ? bq[i] : (i < 2048 ? bk[i - 1024] : bv[i - 2048]);
    dst[i] = v;
}

// ---------- LayerNorm fp32 -> bf16 ----------
__global__ __launch_bounds__(256) void ln_kernel(const float* __restrict__ x,
                                                 const float* __restrict__ gamma,
                                                 const float* __restrict__ beta,
                                                 __hip_bfloat16* __restrict__ out) {
    __shared__ float2 red[4];
    const int row = blockIdx.x, tid = threadIdx.x;
    const float* xr = x + (size_t)row * Dc;
    float4 v = ((const float4*)xr)[tid];
    float s  = v.x + v.y + v.z + v.w;
    float ss = v.x * v.x + v.y * v.y + v.z * v.z + v.w * v.w;
    #pragma unroll
    for (int o = 32; o; o >>= 1) { s += __shfl_down(s, o, 64); ss += __shfl_down(ss, o, 64); }
    if ((tid & 63) == 0) red[tid >> 6] = make_float2(s, ss);
    __syncthreads();
    float2 r0 = red[0], r1 = red[1], r2 = red[2], r3 = red[3];
    s  = r0.x + r1.x + r2.x + r3.x;
    ss = r0.y + r1.y + r2.y + r3.y;
    const float mean = s * (1.0f / Dc);
    const float var  = ss * (1.0f / Dc) - mean * mean;
    const float inv  = rsqrtf(var + LNEPS);
    float4 g  = ((const float4*)gamma)[tid];
    float4 bb = ((const float4*)beta)[tid];
    __hip_bfloat16* orow = out + (size_t)row * Dc + tid * 4;
    orow[0] = __float2bfloat16((v.x - mean) * inv * g.x + bb.x);
    orow[1] = __float2bfloat16((v.y - mean) * inv * g.y + bb.y);
    orow[2] = __float2bfloat16((v.z - mean) * inv * g.z + bb.z);
    orow[3] = __float2bfloat16((v.w - mean) * inv * g.w + bb.w);
}

// ---------- bf16 MFMA GEMM (m97 structure, 128^2): out-proj + MLP2 (deep-K / small-N) ----------
// EPI: 0 = bias only, 1 = bias+gelu, 2 = bias+fp32-residual
template <int EPI, bool OUT_BF16>
__global__ __launch_bounds__(256) void gemm_kernel(
    const __hip_bfloat16* __restrict__ A, const __hip_bfloat16* __restrict__ Bt,
    const float* __restrict__ bias, const float* __restrict__ resid,
    void* __restrict__ Cout, int M, int N, int K) {
    __shared__ __align__(16) short As[128 * 32];
    __shared__ __align__(16) short Bs[128 * 32];
    const int tid = threadIdx.x;
    const int wave = tid >> 6, lane = tid & 63, quad = lane >> 4, l16 = lane & 15;
    const int m0 = blockIdx.x * 128, n0 = blockIdx.y * 128;
    const int wm = (wave >> 1) * 64, wn = (wave & 1) * 64;
    f32x4 acc[4][4] = {};

    const int srow = wave * 16 + (lane >> 2);
    const int scol = (lane & 3) * 8;
    const short* aSrc0 = (const short*)A  + (size_t)(m0 + srow) * K + scol;
    const short* aSrc1 = aSrc0 + (size_t)64 * K;
    const short* bSrc0 = (const short*)Bt + (size_t)(n0 + srow) * K + scol;
    const short* bSrc1 = bSrc0 + (size_t)64 * K;
    LAS void* ldsA0 = to_lds(&As[(wave * 16) * 32]);
    LAS void* ldsA1 = to_lds(&As[(64 + wave * 16) * 32]);
    LAS void* ldsB0 = to_lds(&Bs[(wave * 16) * 32]);
    LAS void* ldsB1 = to_lds(&Bs[(64 + wave * 16) * 32]);

    for (int k0 = 0; k0 < K; k0 += 32) {
        __builtin_amdgcn_global_load_lds((const GAS void*)(aSrc0 + k0), ldsA0, 16, 0, 0);
        __builtin_amdgcn_global_load_lds((const GAS void*)(aSrc1 + k0), ldsA1, 16, 0, 0);
        __builtin_amdgcn_global_load_lds((const GAS void*)(bSrc0 + k0), ldsB0, 16, 0, 0);
        __builtin_amdgcn_global_load_lds((const GAS void*)(bSrc1 + k0), ldsB1, 16, 0, 0);
        __syncthreads();
        short8 af[4], bfr[4];
        #pragma unroll
        for (int i = 0; i < 4; i++) af[i]  = *(const short8*)&As[(wm + i * 16 + l16) * 32 + quad * 8];
        #pragma unroll
        for (int i = 0; i < 4; i++) bfr[i] = *(const short8*)&Bs[(wn + i * 16 + l16) * 32 + quad * 8];
        #pragma unroll
        for (int i = 0; i < 4; i++)
            #pragma unroll
            for (int j = 0; j < 4; j++)
                acc[i][j] = __builtin_amdgcn_mfma_f32_16x16x32_bf16(af[i], bfr[j], acc[i][j], 0, 0, 0);
        __syncthreads();
    }
    #pragma unroll
    for (int i = 0; i < 4; i++) {
        #pragma unroll
        for (int j = 0; j < 4; j++) {
            const int col = n0 + wn + j * 16 + l16;
            const float bv = bias[col];
            #pragma unroll
            for (int r = 0; r < 4; r++) {
                const int row = m0 + wm + i * 16 + quad * 4 + r;
                float val = acc[i][j][r] + bv;
                if (EPI == 1) val = gelu_exact(val);
                if (EPI == 2) val += resid[(size_t)row * N + col];
                if (OUT_BF16)
                    ((__hip_bfloat16*)Cout)[(size_t)row * N + col] = __float2bfloat16(val);
                else
                    ((float*)Cout)[(size_t)row * N + col] = val;
            }
        }
    }
}

// ---------- 256x256 8-phase bf16 GEMM (T2 3-bit XOR swizzle + T3/T4 counted vmcnt + T5) ----------
template <int EPI, bool OUT_BF16>
__global__ __launch_bounds__(512, 2) void gemm256(
    const __hip_bfloat16* __restrict__ A, const __hip_bfloat16* __restrict__ Bt,
    const float* __restrict__ bias, const float* __restrict__ resid,
    void* __restrict__ Cout, int M, int N, int K) {
    __shared__ __align__(1024) short As[2][256 * 64];
    __shared__ __align__(1024) short Bs[2][256 * 64];
    const int tid = threadIdx.x;
    const int wave = tid >> 6, lane = tid & 63, quad = lane >> 4, l16 = lane & 15;
    const int wm = wave >> 2, wn = wave & 3;
    const int m0 = blockIdx.x * 256, n0 = blockIdx.y * 256;

    // ---- staging geometry ----
    const int subrow = lane >> 3;
    const int scb = (((lane & 7) ^ subrow) << 4);            // pre-swizzled source col byte
    const int arowb[4] = {0, 128, 64, 192};    // A: early0, early1, late0, late1
    const int browb[4] = {0, 128, 32, 160};    // B: early0, early1, late0, late1
    const char* aSrc[4]; const char* bSrc[4];
    int aLds[4], bLds[4];
    #pragma unroll
    for (int i = 0; i < 4; ++i) {
        const int rA = arowb[i] + wave * 8;
        aSrc[i] = (const char*)A + ((size_t)(m0 + rA + subrow) * K) * 2 + scb;
        aLds[i] = rA * 128;
        const int rB = browb[i] + (wave >> 2) * 64 + (wave & 3) * 8;
        bSrc[i] = (const char*)Bt + ((size_t)(n0 + rB + subrow) * K) * 2 + scb;
        bLds[i] = rB * 128;
    }
    const int nt = K >> 6;

    #define STG_A(i, tt, dstbuf) \
        __builtin_amdgcn_global_load_lds((const GAS void*)(aSrc[i] + (size_t)(tt) * 128), \
                                         to_lds((char*)&As[dstbuf][0] + aLds[i]), 16, 0, 0)
    #define STG_B(i, tt, dstbuf) \
        __builtin_amdgcn_global_load_lds((const GAS void*)(bSrc[i] + (size_t)(tt) * 128), \
                                         to_lds((char*)&Bs[dstbuf][0] + bLds[i]), 16, 0, 0)

    // prologue: stage tile 0 fully, oldest-first = consumption order
    STG_A(0, 0, 0); STG_A(1, 0, 0);
    STG_B(0, 0, 0); STG_B(1, 0, 0);
    STG_B(2, 0, 0); STG_B(3, 0, 0);
    STG_A(2, 0, 0); STG_A(3, 0, 0);
    asm volatile("s_waitcnt vmcnt(4)\n\ts_barrier" ::: "memory");   // A/B-early(0) landed

    // ds_read addressing: slot XOR (row&7); two k-halves at cb0 / cb0^64
    const int cb0 = ((quad ^ (l16 & 7)) << 4);
    const int cb1 = cb0 ^ 64;
    f32x4 acc[8][4] = {};

    for (int t = 0; t < nt; ++t) {
        const int cb = t & 1, nb = cb ^ 1;
        const char* Ard = (const char*)&As[cb][0] + (wm * 128 + l16) * 128;
        const char* Brd = (const char*)&Bs[cb][0] + (wn * 64 + l16) * 128;
        const bool stg = (t + 1 < nt);
        short8 af[4][2], bf[4][2];

        // ---- phase 0: Q0 = m0-3 x n0-1 (reads A-early(t), B-early(t)) ----
        #pragma unroll
        for (int mi = 0; mi < 4; ++mi) {
            af[mi][0] = *(const short8*)(Ard + mi * 2048 + cb0);
            af[mi][1] = *(const short8*)(Ard + mi * 2048 + cb1);
        }
        #pragma unroll
        for (int nj = 0; nj < 2; ++nj) {
            bf[nj][0] = *(const short8*)(Brd + nj * 2048 + cb0);
            bf[nj][1] = *(const short8*)(Brd + nj * 2048 + cb1);
        }
        if (stg) {
            STG_A(0, t + 1, nb); STG_A(1, t + 1, nb);
            asm volatile("s_waitcnt vmcnt(4)\n\ts_barrier" ::: "memory");  // B-late(t) landed
        } else {
            asm volatile("s_waitcnt vmcnt(2)\n\ts_barrier" ::: "memory");
        }
        __builtin_amdgcn_s_setprio(1);
        #pragma unroll
        for (int mi = 0; mi < 4; ++mi)
            #pragma unroll
            for (int nj = 0; nj < 2; ++nj) {
                acc[mi][nj] = __builtin_amdgcn_mfma_f32_16x16x32_bf16(af[mi][0], bf[nj][0], acc[mi][nj], 0, 0, 0);
                acc[mi][nj] = __builtin_amdgcn_mfma_f32_16x16x32_bf16(af[mi][1], bf[nj][1], acc[mi][nj], 0, 0, 0);
            }
        __builtin_amdgcn_s_setprio(0);
        asm volatile("s_barrier" ::: "memory");

        // ---- phase 1: Q1 = m0-3 x n2-3 (reads B-late(t)) ----
        #pragma unroll
        for (int nj = 2; nj < 4; ++nj) {
            bf[nj][0] = *(const short8*)(Brd + nj * 2048 + cb0);
            bf[nj][1] = *(const short8*)(Brd + nj * 2048 + cb1);
        }
        if (stg) {
            STG_B(0, t + 1, nb); STG_B(1, t + 1, nb);
            asm volatile("s_waitcnt vmcnt(4)\n\ts_barrier" ::: "memory");  // A-late(t) landed
        } else {
            asm volatile("s_waitcnt vmcnt(0)\n\ts_barrier" ::: "memory");
        }
        __builtin_amdgcn_s_setprio(1);
        #pragma unroll
        for (int mi = 0; mi < 4; ++mi)
            #pragma unroll
            for (int nj = 2; nj < 4; ++nj) {
                acc[mi][nj] = __builtin_amdgcn_mfma_f32_16x16x32_bf16(af[mi][0], bf[nj][0], acc[mi][nj], 0, 0, 0);
                acc[mi][nj] = __builtin_amdgcn_mfma_f32_16x16x32_bf16(af[mi][1], bf[nj][1], acc[mi][nj], 0, 0, 0);
            }
        __builtin_amdgcn_s_setprio(0);
        asm volatile("s_barrier" ::: "memory");

        // ---- phase 2: Q2 = m4-7 x n2-3 (reads A-late(t)) ----
        #pragma unroll
        for (int mi = 0; mi < 4; ++mi) {
            af[mi][0] = *(const short8*)(Ard + (mi + 4) * 2048 + cb0);
            af[mi][1] = *(const short8*)(Ard + (mi + 4) * 2048 + cb1);
        }
        if (stg) { STG_B(2, t + 1, nb); STG_B(3, t + 1, nb); }
        asm volatile("s_barrier" ::: "memory");                            // no wait: ph3 reads nothing
        __builtin_amdgcn_s_setprio(1);
        #pragma unroll
        for (int mi = 0; mi < 4; ++mi)
            #pragma unroll
            for (int nj = 2; nj < 4; ++nj) {
                acc[mi + 4][nj] = __builtin_amdgcn_mfma_f32_16x16x32_bf16(af[mi][0], bf[nj][0], acc[mi + 4][nj], 0, 0, 0);
                acc[mi + 4][nj] = __builtin_amdgcn_mfma_f32_16x16x32_bf16(af[mi][1], bf[nj][1], acc[mi + 4][nj], 0, 0, 0);
            }
        __builtin_amdgcn_s_setprio(0);
        asm volatile("s_barrier" ::: "memory");

        // ---- phase 3: Q3 = m4-7 x n0-1 (registers only) ----
        if (stg) {
            STG_A(2, t + 1, nb); STG_A(3, t + 1, nb);
            asm volatile("s_waitcnt vmcnt(4)\n\ts_barrier" ::: "memory");  // A/B-early(t+1) landed
        } else {
            asm volatile("s_barrier" ::: "memory");
        }
        __builtin_amdgcn_s_setprio(1);
        #pragma unroll
        for (int mi = 0; mi < 4; ++mi)
            #pragma unroll
            for (int nj = 0; nj < 2; ++nj) {
                acc[mi + 4][nj] = __builtin_amdgcn_mfma_f32_16x16x32_bf16(af[mi][0], bf[nj][0], acc[mi + 4][nj], 0, 0, 0);
                acc[mi + 4][nj] = __builtin_amdgcn_mfma_f32_16x16x32_bf16(af[mi][1], bf[nj][1], acc[mi + 4][nj], 0, 0, 0);
            }
        __builtin_amdgcn_s_setprio(0);
        asm volatile("s_barrier" ::: "memory");
    }
    #undef STG_A
    #undef STG_B

    // ---- epilogue ----
    #pragma unroll
    for (int mi = 0; mi < 8; ++mi) {
        #pragma unroll
        for (int nj = 0; nj < 4; ++nj) {
            const int col = n0 + wn * 64 + nj * 16 + l16;
            const float bv = bias[col];
            #pragma unroll
            for (int r = 0; r < 4; ++r) {
                const int row = m0 + wm * 128 + mi * 16 + quad * 4 + r;
                float val = acc[mi][nj][r] + bv;
                if (EPI == 1) val = gelu_exact(val);
                if (EPI == 2) val += resid[(size_t)row * N + col];
                if (OUT_BF16)
                    ((__hip_bfloat16*)Cout)[(size_t)row * N + col] = __float2bfloat16(val);
                else
                    ((float*)Cout)[(size_t)row * N + col] = val;
            }
        }
    }
}

// ---------- flash attention v6: v5 + VALU-diet softcap (cvt_pk_bf16 + exp2 folding) ----------
__global__ __launch_bounds__(512, 4) void flash_attn(const __hip_bfloat16* __restrict__ qkv,
                                                     const __hip_bfloat16* __restrict__ vT,
                                                     __hip_bfloat16* __restrict__ ctx) {
    constexpr int NHD = 3072;
    constexpr int LP = 72;                  // P LDS row stride (shorts)
    __shared__ __align__(1024) short Ks[2][64 * 64];  // [s][h], swizzled
    __shared__ __align__(1024) short Vs[2][64 * 64];  // [h][s], swizzled
    __shared__ __align__(16) short Ps[8 * 32 * LP];   // per-wave [q][s]

    const int tid = threadIdx.x;
    const int wave = tid >> 6, lane = tid & 63, quad = lane >> 4, l16 = lane & 15;
    // XCD-aware bijective remap (512 = 8 XCD x 64): XCD k gets groups bn in [k*8,(k+1)*8)
    const int wg = blockIdx.x;
    const int rb = (wg & 7) * 64 + (wg >> 3);
    const int bx = rb & 7, bn = rb >> 3;
    const int t0 = bx * 256;
    const int bb = bn >> 4, hn = bn & 15;
    const __hip_bfloat16* Qg  = qkv + ((size_t)(bb * Tc + t0)) * NHD + hn * Hc;
    const __hip_bfloat16* Kg  = qkv + (size_t)bb * Tc * NHD + Dc + hn * Hc;
    const __hip_bfloat16* vTg = vT + (size_t)bn * 64 * Tc;

    const int wm = wave * 32;
    short* Psw = Ps + wave * 32 * LP;

    // hoisted Q fragments (used as MFMA B operand: n=q, k=h)
    short8 bq[2][2];
    #pragma unroll
    for (int kt = 0; kt < 2; ++kt)
        #pragma unroll
        for (int i = 0; i < 2; ++i)
            bq[kt][i] = *(const short8*)&Qg[(size_t)(wm + i * 16 + l16) * NHD + kt * 32 + quad * 8];

    // DMA staging geometry: per wave 1 chunk (8 rows x 128B) of K and of V per tile
    const int srow = lane >> 3;
    const int scb = (((lane & 7) ^ srow) << 4);     // pre-swizzled source col byte
    const char* kSrc = (const char*)Kg + (size_t)(wave * 8 + srow) * (NHD * 2) + scb;
    const char* vSrc = (const char*)vTg + (size_t)(wave * 8 + srow) * (Tc * 2) + scb;
    const int ldsOff = wave * 1024;                 // wave-uniform chunk base

    #define STG_KV(tt, b) do { \
        __builtin_amdgcn_global_load_lds((const GAS void*)(kSrc + (size_t)(tt) * 64 * (NHD * 2)), \
                                         to_lds((char*)&Ks[b][0] + ldsOff), 16, 0, 0); \
        __builtin_amdgcn_global_load_lds((const GAS void*)(vSrc + (size_t)(tt) * 128), \
                                         to_lds((char*)&Vs[b][0] + ldsOff), 16, 0, 0); \
    } while (0)

    const short4v ONES4 = {0x3F80, 0x3F80, 0x3F80, 0x3F80};   // bf16 1.0
    short8 ones;
    *(short4v*)&ones = ONES4;
    *((short4v*)&ones + 1) = ONES4;

    f32x4 o_acc[2][4] = {};                 // O: q-block i (2) x h-block ht (4)
    f32x4 l_mf[2]  = {};                    // row sums per q-block

    // softcap poly folded with log2(e): p = 2^(sc*(c0 + c1*u + c2*u^2)), u = sc^2
    constexpr float C0 = 0.18033688011f;    // 0.125 * log2(e)
    constexpr float C1 = -3.75702e-7f;      // -2.60416667e-7 * log2(e)
    constexpr float C2 = 9.39258e-13f;      // 6.51041667e-13 * log2(e)

    // swizzled read slot base: logical slot (kt*4+quad) ^ (l16&7), kt handled by ^64
    const int rslot0 = ((quad ^ (l16 & 7)) << 4);
    const int rslot1 = rslot0 ^ 64;

    STG_KV(0, 0);                            // prologue: tile 0 in flight
    for (int t = 0; t < Tc / 64; ++t) {
        const int cb = t & 1;
        if (t + 1 < Tc / 64) {
            STG_KV(t + 1, cb ^ 1);           // prefetch next tile (buffer freed by prev end-barrier)
            asm volatile("s_waitcnt vmcnt(2)\n\ts_barrier" ::: "memory");   // tile t landed
        } else {
            asm volatile("s_waitcnt vmcnt(0)\n\ts_barrier" ::: "memory");
        }
        const char* Kb = (const char*)&Ks[cb][0];
        const char* Vb = (const char*)&Vs[cb][0];

        // S^T = K Q^T (A = K rows -> m=s, B = Q rows -> n=q), then softcap+exp2 -> Ps[q][s]
        #pragma unroll
        for (int jh = 0; jh < 2; ++jh) {    // j-half: s-blocks {2jh, 2jh+1}
            f32x4 st[2][2] = {};
            #pragma unroll
            for (int kt = 0; kt < 2; ++kt) {
                short8 ak[2];
                #pragma unroll
                for (int jj = 0; jj < 2; ++jj)
                    ak[jj] = *(const short8*)(Kb + ((jh * 2 + jj) * 16 + l16) * 128 + (kt ? rslot1 : rslot0));
                __builtin_amdgcn_s_setprio(1);
                #pragma unroll
                for (int jj = 0; jj < 2; ++jj)
                    #pragma unroll
                    for (int i = 0; i < 2; ++i)
                        st[jj][i] = __builtin_amdgcn_mfma_f32_16x16x32_bf16(ak[jj], bq[kt][i], st[jj][i], 0, 0, 0);
                __builtin_amdgcn_s_setprio(0);
            }
            // epilogue: lane holds 4 consecutive s (quad*4+r) for q = i*16+l16
            #pragma unroll
            for (int jj = 0; jj < 2; ++jj)
                #pragma unroll
                for (int i = 0; i < 2; ++i) {
                    float p[4];
                    #pragma unroll
                    for (int r = 0; r < 4; ++r) {
                        const float sc = st[jj][i][r];
                        const float u  = sc * sc;
                        float tt = sc * fmaf(fmaf(C2, u, C1), u, C0);
                        tt = fminf(tt, 86.5f);
                        p[r] = exp2f(tt);
                    }
                    unsigned pk0, pk1;
                    asm("v_cvt_pk_bf16_f32 %0, %1, %2" : "=v"(pk0) : "v"(p[0]), "v"(p[1]));
                    asm("v_cvt_pk_bf16_f32 %0, %1, %2" : "=v"(pk1) : "v"(p[2]), "v"(p[3]));
                    u32x2 pkv;
                    pkv.x = pk0; pkv.y = pk1;
                    *(u32x2*)&Psw[(i * 16 + l16) * LP + (jh * 2 + jj) * 16 + quad * 4] = pkv;
                }
        }
        asm volatile("" ::: "memory");      // order P writes before P reads (wave-private)

        // O += P V, l += P * ones   (A = P[q][s], B = Vs[h][s])
        #pragma unroll
        for (int kt = 0; kt < 2; ++kt) {
            short8 ap[2], bv_[4];
            #pragma unroll
            for (int i = 0; i < 2; ++i)
                ap[i] = *(const short8*)&Psw[(i * 16 + l16) * LP + kt * 32 + quad * 8];
            #pragma unroll
            for (int ht = 0; ht < 4; ++ht)
                bv_[ht] = *(const short8*)(Vb + (ht * 16 + l16) * 128 + (kt ? rslot1 : rslot0));
            __builtin_amdgcn_s_setprio(1);
            #pragma unroll
            for (int i = 0; i < 2; ++i)
                l_mf[i] = __builtin_amdgcn_mfma_f32_16x16x32_bf16(ap[i], ones, l_mf[i], 0, 0, 0);
            #pragma unroll
            for (int i = 0; i < 2; ++i)
                #pragma unroll
                for (int ht = 0; ht < 4; ++ht)
                    o_acc[i][ht] = __builtin_amdgcn_mfma_f32_16x16x32_bf16(ap[i], bv_[ht], o_acc[i][ht], 0, 0, 0);
            __builtin_amdgcn_s_setprio(0);
        }
        asm volatile("s_barrier" ::: "memory");   // all waves done with buf[cb] before next DMA overwrites
    }
    #undef STG_KV

    // normalize + store (l_mf rows align with o_acc rows; no cross-lane reduce needed)
    #pragma unroll
    for (int i = 0; i < 2; ++i) {
        float linv[4];
        #pragma unroll
        for (int r = 0; r < 4; ++r) linv[r] = 1.0f / l_mf[i][r];
        #pragma unroll
        for (int ht = 0; ht < 4; ++ht)
            #pragma unroll
            for (int r = 0; r < 4; ++r) {
                const int row = t0 + wm + i * 16 + quad * 4 + r;
                const int col = hn * Hc + ht * 16 + l16;
                ctx[((size_t)(bb * Tc + row)) * Dc + col] =
                    __float2bfloat16(o_acc[i][ht][r] * linv[r]);
            }
    }
}

extern "C" void kernel_launch(void* const* d_in, const int* in_sizes, int n_in,
                              void* d_out, int out_size, void* d_ws, size_t ws_size,
                              hipStream_t stream) {
    const float* inputs = (const float*)d_in[0];
    const float* ln1_g  = (const float*)d_in[1];
    const float* ln1_b  = (const float*)d_in[2];
    const float* wq     = (const float*)d_in[3];
    const float* bq     = (const float*)d_in[4];
    const float* wk     = (const float*)d_in[5];
    const float* bk     = (const float*)d_in[6];
    const float* wv     = (const float*)d_in[7];
    const float* bv     = (const float*)d_in[8];
    const float* wo     = (const float*)d_in[9];
    const float* bo     = (const float*)d_in[10];
    const float* ln2_g  = (const float*)d_in[11];
    const float* ln2_b  = (const float*)d_in[12];
    const float* w1     = (const float*)d_in[13];
    const float* b1     = (const float*)d_in[14];
    const float* w2     = (const float*)d_in[15];
    const float* b2     = (const float*)d_in[16];

    char* ws = (char*)d_ws;
    auto alloc = [&](size_t bytes) {
        char* p = ws;
        ws += (bytes + 255) & ~(size_t)255;
        return p;
    };
    __hip_bfloat16* wqkv_t = (__hip_bfloat16*)alloc((size_t)3072 * 1024 * 2);
    __hip_bfloat16* wo_t   = (__hip_bfloat16*)alloc((size_t)1024 * 1024 * 2);
    __hip_bfloat16* w1_t   = (__hip_bfloat16*)alloc((size_t)4096 * 1024 * 2);
    __hip_bfloat16* w2_t   = (__hip_bfloat16*)alloc((size_t)4096 * 1024 * 2);
    float*          bqkv   = (float*)alloc(3072 * 4);
    __hip_bfloat16* xn     = (__hip_bfloat16*)alloc((size_t)Mrows * 1024 * 2);
    __hip_bfloat16* qkv    = (__hip_bfloat16*)alloc((size_t)Mrows * 3072 * 2);
    __hip_bfloat16* vTr    = (__hip_bfloat16*)alloc((size_t)64 * 64 * Tc * 2);
    __hip_bfloat16* ctx    = (__hip_bfloat16*)alloc((size_t)Mrows * 1024 * 2);
    float*          xres   = (float*)alloc((size_t)Mrows * 1024 * 4);
    __hip_bfloat16* y1     = qkv;   // alias: qkv dead after attention+out-proj

    dim3 blk(256);
    transpose_cvt<<<dim3(32, 32), blk, 0, stream>>>(wq, wqkv_t, 1024, 1024);
    transpose_cvt<<<dim3(32, 32), blk, 0, stream>>>(wk, wqkv_t + 1024 * 1024, 1024, 1024);
    transpose_cvt<<<dim3(32, 32), blk, 0, stream>>>(wv, wqkv_t + 2048 * 1024, 1024, 1024);
    transpose_cvt<<<dim3(32, 32), blk, 0, stream>>>(wo, wo_t, 1024, 1024);
    transpose_cvt<<<dim3(128, 32), blk, 0, stream>>>(w1, w1_t, 1024, 4096);
    transpose_cvt<<<dim3(32, 128), blk, 0, stream>>>(w2, w2_t, 4096, 1024);
    concat_bias<<<dim3(12), blk, 0, stream>>>(bq, bk, bv, bqkv);

    ln_kernel<<<dim3(Mrows), blk, 0, stream>>>(inputs, ln1_g, ln1_b, xn);
    gemm256<0, true><<<dim3(32, 12), dim3(512), 0, stream>>>(xn, wqkv_t, bqkv, nullptr, qkv, Mrows, 3072, 1024);
    transpose_v<<<dim3(64, 2, 64), blk, 0, stream>>>(qkv, vTr);
    flash_attn<<<dim3(512), dim3(512), 0, stream>>>(qkv, vTr, ctx);
    gemm_kernel<2, false><<<dim3(64, 8), blk, 0, stream>>>(ctx, wo_t, bo, inputs, xres, Mrows, 1024, 1024);
    ln_kernel<<<dim3(Mrows), blk, 0, stream>>>(xres, ln2_g, ln2_b, xn);
    gemm256<1, true><<<dim3(32, 16), dim3(512), 0, stream>>>(xn, w1_t, b1, nullptr, y1, Mrows, 4096, 1024);
    gemm_kernel<2, false><<<dim3(64, 8), blk, 0, stream>>>(y1, w2_t, b2, xres, (float*)d_out, Mrows, 1024, 4096);
}

// Round 6
// 545.144 us; speedup vs baseline: 1.0864x; 1.0864x over previous
//
#include <hip/hip_runtime.h>
#include <hip/hip_bf16.h>
#include <math.h>

typedef __attribute__((ext_vector_type(8))) short short8;
typedef __attribute__((ext_vector_type(4))) short short4v;
typedef __attribute__((ext_vector_type(4))) float f32x4;

#define GAS __attribute__((address_space(1)))
#define LAS __attribute__((address_space(3)))

__device__ __forceinline__ LAS void* to_lds(void* p) {
    return (LAS void*)(unsigned)(uintptr_t)p;
}

constexpr int Bc = 4, Tc = 2048, Dc = 1024, Nheads = 16, Hc = 64, Fc = 4096;
constexpr int Mrows = Bc * Tc;          // 8192
constexpr float LNEPS = 1e-6f;

__device__ __forceinline__ float gelu_exact(float x) {
    return 0.5f * x * (1.0f + erff(x * 0.70710678118654752440f));
}

// ---------- fp32 [K,N] -> bf16 [N,K] transpose+convert ----------
__global__ __launch_bounds__(256) void transpose_cvt(const float* __restrict__ src,
                                                     __hip_bfloat16* __restrict__ dst,
                                                     int K, int N) {
    __shared__ float tile[32][33];
    const int n0 = blockIdx.x * 32, k0 = blockIdx.y * 32;
    const int tx = threadIdx.x & 31, ty = threadIdx.x >> 5;   // 32 x 8
    #pragma unroll
    for (int i = 0; i < 32; i += 8)
        tile[ty + i][tx] = src[(size_t)(k0 + ty + i) * N + (n0 + tx)];
    __syncthreads();
    #pragma unroll
    for (int i = 0; i < 32; i += 8)
        dst[(size_t)(n0 + ty + i) * K + (k0 + tx)] = __float2bfloat16(tile[tx][ty + i]);
}

// ---------- V pre-transpose: qkv V-slice [t][h] -> vT[b][n][h][t] (bf16) ----------
__global__ __launch_bounds__(256) void transpose_v(const __hip_bfloat16* __restrict__ qkv,
                                                   __hip_bfloat16* __restrict__ vT) {
    __shared__ short tile[32][33];
    const int t0 = blockIdx.x * 32, h0 = blockIdx.y * 32, bn = blockIdx.z;
    const int b = bn >> 4, n = bn & 15;
    const short* src = (const short*)qkv + (size_t)b * Tc * 3072 + 2048 + n * 64;
    short* dst = (short*)vT + (size_t)bn * 64 * Tc;
    const int tx = threadIdx.x & 31, ty = threadIdx.x >> 5;
    #pragma unroll
    for (int i = 0; i < 32; i += 8)
        tile[ty + i][tx] = src[(size_t)(t0 + ty + i) * 3072 + h0 + tx];
    __syncthreads();
    #pragma unroll
    for (int i = 0; i < 32; i += 8)
        dst[(size_t)(h0 + ty + i) * Tc + t0 + tx] = tile[tx][ty + i];
}

// ---------- concat bq,bk,bv -> [3072] ----------
__global__ void concat_bias(const float* __restrict__ bq, const float* __restrict__ bk,
                            const float* __restrict__ bv, float* __restrict__ dst) {
    int i = blockIdx.x * 256 + threadIdx.x;   // 3072 total
    float v = (i < 1024) ? bq[i] : (i < 2048 ? bk[i - 1024] : bv[i - 2048]);
    dst[i] = v;
}

// ---------- LayerNorm fp32 -> bf16 ----------
__global__ __launch_bounds__(256) void ln_kernel(const float* __restrict__ x,
                                                 const float* __restrict__ gamma,
                                                 const float* __restrict__ beta,
                                                 __hip_bfloat16* __restrict__ out) {
    __shared__ float2 red[4];
    const int row = blockIdx.x, tid = threadIdx.x;
    const float* xr = x + (size_t)row * Dc;
    float4 v = ((const float4*)xr)[tid];
    float s  = v.x + v.y + v.z + v.w;
    float ss = v.x * v.x + v.y * v.y + v.z * v.z + v.w * v.w;
    #pragma unroll
    for (int o = 32; o; o >>= 1) { s += __shfl_down(s, o, 64); ss += __shfl_down(ss, o, 64); }
    if ((tid & 63) == 0) red[tid >> 6] = make_float2(s, ss);
    __syncthreads();
    float2 r0 = red[0], r1 = red[1], r2 = red[2], r3 = red[3];
    s  = r0.x + r1.x + r2.x + r3.x;
    ss = r0.y + r1.y + r2.y + r3.y;
    const float mean = s * (1.0f / Dc);
    const float var  = ss * (1.0f / Dc) - mean * mean;
    const float inv  = rsqrtf(var + LNEPS);
    float4 g  = ((const float4*)gamma)[tid];
    float4 bb = ((const float4*)beta)[tid];
    __hip_bfloat16* orow = out + (size_t)row * Dc + tid * 4;
    orow[0] = __float2bfloat16((v.x - mean) * inv * g.x + bb.x);
    orow[1] = __float2bfloat16((v.y - mean) * inv * g.y + bb.y);
    orow[2] = __float2bfloat16((v.z - mean) * inv * g.z + bb.z);
    orow[3] = __float2bfloat16((v.w - mean) * inv * g.w + bb.w);
}

// ---------- 256x256 8-phase bf16 GEMM (T2 3-bit XOR swizzle + T3/T4 counted vmcnt + T5) ----------
template <int EPI, bool OUT_BF16>
__global__ __launch_bounds__(512, 2) void gemm256(
    const __hip_bfloat16* __restrict__ A, const __hip_bfloat16* __restrict__ Bt,
    const float* __restrict__ bias, const float* __restrict__ resid,
    void* __restrict__ Cout, int M, int N, int K) {
    __shared__ __align__(1024) short As[2][256 * 64];
    __shared__ __align__(1024) short Bs[2][256 * 64];
    const int tid = threadIdx.x;
    const int wave = tid >> 6, lane = tid & 63, quad = lane >> 4, l16 = lane & 15;
    const int wm = wave >> 2, wn = wave & 3;
    const int m0 = blockIdx.x * 256, n0 = blockIdx.y * 256;

    // ---- staging geometry ----
    const int subrow = lane >> 3;
    const int scb = (((lane & 7) ^ subrow) << 4);            // pre-swizzled source col byte
    const int arowb[4] = {0, 128, 64, 192};    // A: early0, early1, late0, late1
    const int browb[4] = {0, 128, 32, 160};    // B: early0, early1, late0, late1
    const char* aSrc[4]; const char* bSrc[4];
    int aLds[4], bLds[4];
    #pragma unroll
    for (int i = 0; i < 4; ++i) {
        const int rA = arowb[i] + wave * 8;
        aSrc[i] = (const char*)A + ((size_t)(m0 + rA + subrow) * K) * 2 + scb;
        aLds[i] = rA * 128;
        const int rB = browb[i] + (wave >> 2) * 64 + (wave & 3) * 8;
        bSrc[i] = (const char*)Bt + ((size_t)(n0 + rB + subrow) * K) * 2 + scb;
        bLds[i] = rB * 128;
    }
    const int nt = K >> 6;

    #define STG_A(i, tt, dstbuf) \
        __builtin_amdgcn_global_load_lds((const GAS void*)(aSrc[i] + (size_t)(tt) * 128), \
                                         to_lds((char*)&As[dstbuf][0] + aLds[i]), 16, 0, 0)
    #define STG_B(i, tt, dstbuf) \
        __builtin_amdgcn_global_load_lds((const GAS void*)(bSrc[i] + (size_t)(tt) * 128), \
                                         to_lds((char*)&Bs[dstbuf][0] + bLds[i]), 16, 0, 0)

    // prologue: stage tile 0 fully, oldest-first = consumption order
    STG_A(0, 0, 0); STG_A(1, 0, 0);
    STG_B(0, 0, 0); STG_B(1, 0, 0);
    STG_B(2, 0, 0); STG_B(3, 0, 0);
    STG_A(2, 0, 0); STG_A(3, 0, 0);
    asm volatile("s_waitcnt vmcnt(4)\n\ts_barrier" ::: "memory");   // A/B-early(0) landed

    // ds_read addressing: slot XOR (row&7); two k-halves at cb0 / cb0^64
    const int cb0 = ((quad ^ (l16 & 7)) << 4);
    const int cb1 = cb0 ^ 64;
    f32x4 acc[8][4] = {};

    for (int t = 0; t < nt; ++t) {
        const int cb = t & 1, nb = cb ^ 1;
        const char* Ard = (const char*)&As[cb][0] + (wm * 128 + l16) * 128;
        const char* Brd = (const char*)&Bs[cb][0] + (wn * 64 + l16) * 128;
        const bool stg = (t + 1 < nt);
        short8 af[4][2], bf[4][2];

        // ---- phase 0: Q0 = m0-3 x n0-1 (reads A-early(t), B-early(t)) ----
        #pragma unroll
        for (int mi = 0; mi < 4; ++mi) {
            af[mi][0] = *(const short8*)(Ard + mi * 2048 + cb0);
            af[mi][1] = *(const short8*)(Ard + mi * 2048 + cb1);
        }
        #pragma unroll
        for (int nj = 0; nj < 2; ++nj) {
            bf[nj][0] = *(const short8*)(Brd + nj * 2048 + cb0);
            bf[nj][1] = *(const short8*)(Brd + nj * 2048 + cb1);
        }
        if (stg) {
            STG_A(0, t + 1, nb); STG_A(1, t + 1, nb);
            asm volatile("s_waitcnt vmcnt(4)\n\ts_barrier" ::: "memory");  // B-late(t) landed
        } else {
            asm volatile("s_waitcnt vmcnt(2)\n\ts_barrier" ::: "memory");
        }
        __builtin_amdgcn_s_setprio(1);
        #pragma unroll
        for (int mi = 0; mi < 4; ++mi)
            #pragma unroll
            for (int nj = 0; nj < 2; ++nj) {
                acc[mi][nj] = __builtin_amdgcn_mfma_f32_16x16x32_bf16(af[mi][0], bf[nj][0], acc[mi][nj], 0, 0, 0);
                acc[mi][nj] = __builtin_amdgcn_mfma_f32_16x16x32_bf16(af[mi][1], bf[nj][1], acc[mi][nj], 0, 0, 0);
            }
        __builtin_amdgcn_s_setprio(0);
        asm volatile("s_barrier" ::: "memory");

        // ---- phase 1: Q1 = m0-3 x n2-3 (reads B-late(t)) ----
        #pragma unroll
        for (int nj = 2; nj < 4; ++nj) {
            bf[nj][0] = *(const short8*)(Brd + nj * 2048 + cb0);
            bf[nj][1] = *(const short8*)(Brd + nj * 2048 + cb1);
        }
        if (stg) {
            STG_B(0, t + 1, nb); STG_B(1, t + 1, nb);
            asm volatile("s_waitcnt vmcnt(4)\n\ts_barrier" ::: "memory");  // A-late(t) landed
        } else {
            asm volatile("s_waitcnt vmcnt(0)\n\ts_barrier" ::: "memory");
        }
        __builtin_amdgcn_s_setprio(1);
        #pragma unroll
        for (int mi = 0; mi < 4; ++mi)
            #pragma unroll
            for (int nj = 2; nj < 4; ++nj) {
                acc[mi][nj] = __builtin_amdgcn_mfma_f32_16x16x32_bf16(af[mi][0], bf[nj][0], acc[mi][nj], 0, 0, 0);
                acc[mi][nj] = __builtin_amdgcn_mfma_f32_16x16x32_bf16(af[mi][1], bf[nj][1], acc[mi][nj], 0, 0, 0);
            }
        __builtin_amdgcn_s_setprio(0);
        asm volatile("s_barrier" ::: "memory");

        // ---- phase 2: Q2 = m4-7 x n2-3 (reads A-late(t)) ----
        #pragma unroll
        for (int mi = 0; mi < 4; ++mi) {
            af[mi][0] = *(const short8*)(Ard + (mi + 4) * 2048 + cb0);
            af[mi][1] = *(const short8*)(Ard + (mi + 4) * 2048 + cb1);
        }
        if (stg) { STG_B(2, t + 1, nb); STG_B(3, t + 1, nb); }
        asm volatile("s_barrier" ::: "memory");                            // no wait: ph3 reads nothing
        __builtin_amdgcn_s_setprio(1);
        #pragma unroll
        for (int mi = 0; mi < 4; ++mi)
            #pragma unroll
            for (int nj = 2; nj < 4; ++nj) {
                acc[mi + 4][nj] = __builtin_amdgcn_mfma_f32_16x16x32_bf16(af[mi][0], bf[nj][0], acc[mi + 4][nj], 0, 0, 0);
                acc[mi + 4][nj] = __builtin_amdgcn_mfma_f32_16x16x32_bf16(af[mi][1], bf[nj][1], acc[mi + 4][nj], 0, 0, 0);
            }
        __builtin_amdgcn_s_setprio(0);
        asm volatile("s_barrier" ::: "memory");

        // ---- phase 3: Q3 = m4-7 x n0-1 (registers only) ----
        if (stg) {
            STG_A(2, t + 1, nb); STG_A(3, t + 1, nb);
            asm volatile("s_waitcnt vmcnt(4)\n\ts_barrier" ::: "memory");  // A/B-early(t+1) landed
        } else {
            asm volatile("s_barrier" ::: "memory");
        }
        __builtin_amdgcn_s_setprio(1);
        #pragma unroll
        for (int mi = 0; mi < 4; ++mi)
            #pragma unroll
            for (int nj = 0; nj < 2; ++nj) {
                acc[mi + 4][nj] = __builtin_amdgcn_mfma_f32_16x16x32_bf16(af[mi][0], bf[nj][0], acc[mi + 4][nj], 0, 0, 0);
                acc[mi + 4][nj] = __builtin_amdgcn_mfma_f32_16x16x32_bf16(af[mi][1], bf[nj][1], acc[mi + 4][nj], 0, 0, 0);
            }
        __builtin_amdgcn_s_setprio(0);
        asm volatile("s_barrier" ::: "memory");
    }
    #undef STG_A
    #undef STG_B

    // ---- epilogue ----
    #pragma unroll
    for (int mi = 0; mi < 8; ++mi) {
        #pragma unroll
        for (int nj = 0; nj < 4; ++nj) {
            const int col = n0 + wn * 64 + nj * 16 + l16;
            const float bv = bias[col];
            #pragma unroll
            for (int r = 0; r < 4; ++r) {
                const int row = m0 + wm * 128 + mi * 16 + quad * 4 + r;
                float val = acc[mi][nj][r] + bv;
                if (EPI == 1) val = gelu_exact(val);
                if (EPI == 2) val += resid[(size_t)row * N + col];
                if (OUT_BF16)
                    ((__hip_bfloat16*)Cout)[(size_t)row * N + col] = __float2bfloat16(val);
                else
                    ((float*)Cout)[(size_t)row * N + col] = val;
            }
        }
    }
}

// ---------- 256x128 4-phase bf16 GEMM: full-chip grid for N=1024 outputs ----------
// Same schedule/swizzle as gemm256, tile BN=128: grid (M/256, N/128) = 256 blocks.
// LDS 96 KiB (1 block/CU). Per wave: out 128x32, acc[8][2]; 6 staged loads/tile
// (A-e0,A-e1,B-e,B-l,A-l0,A-l1). Phases: ph0 mi0-3 x nj0 (A-e,B-e); ph1 mi0-3 x nj1
// (B-l); ph2 mi4-7 x nj1 (A-l); ph3 mi4-7 x nj0 (regs). Counted vmcnt throughout.
template <int EPI, bool OUT_BF16>
__global__ __launch_bounds__(512, 2) void gemm256x128(
    const __hip_bfloat16* __restrict__ A, const __hip_bfloat16* __restrict__ Bt,
    const float* __restrict__ bias, const float* __restrict__ resid,
    void* __restrict__ Cout, int M, int N, int K) {
    __shared__ __align__(1024) short As[2][256 * 64];
    __shared__ __align__(1024) short Bs[2][128 * 64];
    const int tid = threadIdx.x;
    const int wave = tid >> 6, lane = tid & 63, quad = lane >> 4, l16 = lane & 15;
    const int wm = wave >> 2, wn = wave & 3;
    const int m0 = blockIdx.x * 256, n0 = blockIdx.y * 128;

    const int subrow = lane >> 3;
    const int scb = (((lane & 7) ^ subrow) << 4);
    const int arowb[4] = {0, 128, 64, 192};    // A: early0, early1, late0, late1
    const char* aSrc[4]; int aLds[4];
    #pragma unroll
    for (int i = 0; i < 4; ++i) {
        const int rA = arowb[i] + wave * 8;
        aSrc[i] = (const char*)A + ((size_t)(m0 + rA + subrow) * K) * 2 + scb;
        aLds[i] = rA * 128;
    }
    // B chunks: early = rows with (row%32)<16, late = rest (8-row chunks)
    const char* bSrc[2]; int bLds[2];
    #pragma unroll
    for (int i = 0; i < 2; ++i) {
        const int rB = (wave >> 1) * 32 + (wave & 1) * 8 + i * 16;
        bSrc[i] = (const char*)Bt + ((size_t)(n0 + rB + subrow) * K) * 2 + scb;
        bLds[i] = rB * 128;
    }
    const int nt = K >> 6;

    #define STG_A(i, tt, dstbuf) \
        __builtin_amdgcn_global_load_lds((const GAS void*)(aSrc[i] + (size_t)(tt) * 128), \
                                         to_lds((char*)&As[dstbuf][0] + aLds[i]), 16, 0, 0)
    #define STG_B(i, tt, dstbuf) \
        __builtin_amdgcn_global_load_lds((const GAS void*)(bSrc[i] + (size_t)(tt) * 128), \
                                         to_lds((char*)&Bs[dstbuf][0] + bLds[i]), 16, 0, 0)

    // prologue: oldest-first = consumption order (A-e, B-e, B-l, A-l)
    STG_A(0, 0, 0); STG_A(1, 0, 0);
    STG_B(0, 0, 0); STG_B(1, 0, 0);
    STG_A(2, 0, 0); STG_A(3, 0, 0);
    asm volatile("s_waitcnt vmcnt(3)\n\ts_barrier" ::: "memory");   // A-e(0)+B-e(0) landed

    const int cb0 = ((quad ^ (l16 & 7)) << 4);
    const int cb1 = cb0 ^ 64;
    f32x4 acc[8][2] = {};

    for (int t = 0; t < nt; ++t) {
        const int cb = t & 1, nb = cb ^ 1;
        const char* Ard = (const char*)&As[cb][0] + (wm * 128 + l16) * 128;
        const char* Brd = (const char*)&Bs[cb][0] + (wn * 32 + l16) * 128;
        const bool stg = (t + 1 < nt);
        short8 af[4][2], bf[2][2];

        // ---- phase 0: mi0-3 x nj0 (reads A-early(t), B-early(t)) ----
        #pragma unroll
        for (int mi = 0; mi < 4; ++mi) {
            af[mi][0] = *(const short8*)(Ard + mi * 2048 + cb0);
            af[mi][1] = *(const short8*)(Ard + mi * 2048 + cb1);
        }
        bf[0][0] = *(const short8*)(Brd + cb0);
        bf[0][1] = *(const short8*)(Brd + cb1);
        if (stg) {
            STG_A(0, t + 1, nb); STG_A(1, t + 1, nb);
            asm volatile("s_waitcnt vmcnt(4)\n\ts_barrier" ::: "memory");  // B-late(t) landed
        } else {
            asm volatile("s_waitcnt vmcnt(2)\n\ts_barrier" ::: "memory");  // B-late(t) landed
        }
        __builtin_amdgcn_s_setprio(1);
        #pragma unroll
        for (int mi = 0; mi < 4; ++mi) {
            acc[mi][0] = __builtin_amdgcn_mfma_f32_16x16x32_bf16(af[mi][0], bf[0][0], acc[mi][0], 0, 0, 0);
            acc[mi][0] = __builtin_amdgcn_mfma_f32_16x16x32_bf16(af[mi][1], bf[0][1], acc[mi][0], 0, 0, 0);
        }
        __builtin_amdgcn_s_setprio(0);
        asm volatile("s_barrier" ::: "memory");

        // ---- phase 1: mi0-3 x nj1 (reads B-late(t)) ----
        bf[1][0] = *(const short8*)(Brd + 2048 + cb0);
        bf[1][1] = *(const short8*)(Brd + 2048 + cb1);
        if (stg) {
            STG_B(0, t + 1, nb); STG_B(1, t + 1, nb);
            asm volatile("s_waitcnt vmcnt(4)\n\ts_barrier" ::: "memory");  // A-late(t) landed
        } else {
            asm volatile("s_waitcnt vmcnt(0)\n\ts_barrier" ::: "memory");
        }
        __builtin_amdgcn_s_setprio(1);
        #pragma unroll
        for (int mi = 0; mi < 4; ++mi) {
            acc[mi][1] = __builtin_amdgcn_mfma_f32_16x16x32_bf16(af[mi][0], bf[1][0], acc[mi][1], 0, 0, 0);
            acc[mi][1] = __builtin_amdgcn_mfma_f32_16x16x32_bf16(af[mi][1], bf[1][1], acc[mi][1], 0, 0, 0);
        }
        __builtin_amdgcn_s_setprio(0);
        asm volatile("s_barrier" ::: "memory");

        // ---- phase 2: mi4-7 x nj1 (reads A-late(t)) ----
        #pragma unroll
        for (int mi = 0; mi < 4; ++mi) {
            af[mi][0] = *(const short8*)(Ard + (mi + 4) * 2048 + cb0);
            af[mi][1] = *(const short8*)(Ard + (mi + 4) * 2048 + cb1);
        }
        if (stg) { STG_A(2, t + 1, nb); STG_A(3, t + 1, nb); }
        asm volatile("s_barrier" ::: "memory");
        __builtin_amdgcn_s_setprio(1);
        #pragma unroll
        for (int mi = 0; mi < 4; ++mi) {
            acc[mi + 4][1] = __builtin_amdgcn_mfma_f32_16x16x32_bf16(af[mi][0], bf[1][0], acc[mi + 4][1], 0, 0, 0);
            acc[mi + 4][1] = __builtin_amdgcn_mfma_f32_16x16x32_bf16(af[mi][1], bf[1][1], acc[mi + 4][1], 0, 0, 0);
        }
        __builtin_amdgcn_s_setprio(0);
        asm volatile("s_barrier" ::: "memory");

        // ---- phase 3: mi4-7 x nj0 (registers only) ----
        if (stg) {
            asm volatile("s_waitcnt vmcnt(2)\n\ts_barrier" ::: "memory");  // A-e(t+1)+B(t+1) landed
        } else {
            asm volatile("s_barrier" ::: "memory");
        }
        __builtin_amdgcn_s_setprio(1);
        #pragma unroll
        for (int mi = 0; mi < 4; ++mi) {
            acc[mi + 4][0] = __builtin_amdgcn_mfma_f32_16x16x32_bf16(af[mi][0], bf[0][0], acc[mi + 4][0], 0, 0, 0);
            acc[mi + 4][0] = __builtin_amdgcn_mfma_f32_16x16x32_bf16(af[mi][1], bf[0][1], acc[mi + 4][0], 0, 0, 0);
        }
        __builtin_amdgcn_s_setprio(0);
        asm volatile("s_barrier" ::: "memory");
    }
    #undef STG_A
    #undef STG_B

    // ---- epilogue ----
    #pragma unroll
    for (int mi = 0; mi < 8; ++mi) {
        #pragma unroll
        for (int nj = 0; nj < 2; ++nj) {
            const int col = n0 + wn * 32 + nj * 16 + l16;
            const float bv = bias[col];
            #pragma unroll
            for (int r = 0; r < 4; ++r) {
                const int row = m0 + wm * 128 + mi * 16 + quad * 4 + r;
                float val = acc[mi][nj][r] + bv;
                if (EPI == 1) val = gelu_exact(val);
                if (EPI == 2) val += resid[(size_t)row * N + col];
                if (OUT_BF16)
                    ((__hip_bfloat16*)Cout)[(size_t)row * N + col] = __float2bfloat16(val);
                else
                    ((float*)Cout)[(size_t)row * N + col] = val;
            }
        }
    }
}

// ---------- flash attention v5 (proven 120us): 8-wave, DMA K/V dbuf + XOR swizzle, XCD remap ----------
__global__ __launch_bounds__(512, 4) void flash_attn(const __hip_bfloat16* __restrict__ qkv,
                                                     const __hip_bfloat16* __restrict__ vT,
                                                     __hip_bfloat16* __restrict__ ctx) {
    constexpr int NHD = 3072;
    constexpr int LP = 72;                  // P LDS row stride (shorts)
    __shared__ __align__(1024) short Ks[2][64 * 64];  // [s][h], swizzled
    __shared__ __align__(1024) short Vs[2][64 * 64];  // [h][s], swizzled
    __shared__ __align__(16) short Ps[8 * 32 * LP];   // per-wave [q][s]

    const int tid = threadIdx.x;
    const int wave = tid >> 6, lane = tid & 63, quad = lane >> 4, l16 = lane & 15;
    // XCD-aware bijective remap (512 = 8 XCD x 64): XCD k gets groups bn in [k*8,(k+1)*8)
    const int wg = blockIdx.x;
    const int rb = (wg & 7) * 64 + (wg >> 3);
    const int bx = rb & 7, bn = rb >> 3;
    const int t0 = bx * 256;
    const int bb = bn >> 4, hn = bn & 15;
    const __hip_bfloat16* Qg  = qkv + ((size_t)(bb * Tc + t0)) * NHD + hn * Hc;
    const __hip_bfloat16* Kg  = qkv + (size_t)bb * Tc * NHD + Dc + hn * Hc;
    const __hip_bfloat16* vTg = vT + (size_t)bn * 64 * Tc;

    const int wm = wave * 32;
    short* Psw = Ps + wave * 32 * LP;

    // hoisted Q fragments (used as MFMA B operand: n=q, k=h)
    short8 bq[2][2];
    #pragma unroll
    for (int kt = 0; kt < 2; ++kt)
        #pragma unroll
        for (int i = 0; i < 2; ++i)
            bq[kt][i] = *(const short8*)&Qg[(size_t)(wm + i * 16 + l16) * NHD + kt * 32 + quad * 8];

    // DMA staging geometry: per wave 1 chunk (8 rows x 128B) of K and of V per tile
    const int srow = lane >> 3;
    const int scb = (((lane & 7) ^ srow) << 4);     // pre-swizzled source col byte
    const char* kSrc = (const char*)Kg + (size_t)(wave * 8 + srow) * (NHD * 2) + scb;
    const char* vSrc = (const char*)vTg + (size_t)(wave * 8 + srow) * (Tc * 2) + scb;
    const int ldsOff = wave * 1024;                 // wave-uniform chunk base

    #define STG_KV(tt, b) do { \
        __builtin_amdgcn_global_load_lds((const GAS void*)(kSrc + (size_t)(tt) * 64 * (NHD * 2)), \
                                         to_lds((char*)&Ks[b][0] + ldsOff), 16, 0, 0); \
        __builtin_amdgcn_global_load_lds((const GAS void*)(vSrc + (size_t)(tt) * 128), \
                                         to_lds((char*)&Vs[b][0] + ldsOff), 16, 0, 0); \
    } while (0)

    const short4v ONES4 = {0x3F80, 0x3F80, 0x3F80, 0x3F80};   // bf16 1.0
    short8 ones;
    *(short4v*)&ones = ONES4;
    *((short4v*)&ones + 1) = ONES4;

    f32x4 o_acc[2][4] = {};                 // O: q-block i (2) x h-block ht (4)
    f32x4 l_mf[2]  = {};                    // row sums per q-block

    // softcap poly: p = exp(sc*(c0 + c1*u + c2*u^2)), u = sc^2  [sc = raw QK accum]
    constexpr float C0 = 0.125f;
    constexpr float C1 = -2.60416667e-7f;
    constexpr float C2 = 6.51041667e-13f;

    // swizzled read slot base: logical slot (kt*4+quad) ^ (l16&7), kt handled by ^64
    const int rslot0 = ((quad ^ (l16 & 7)) << 4);
    const int rslot1 = rslot0 ^ 64;

    STG_KV(0, 0);                            // prologue: tile 0 in flight
    for (int t = 0; t < Tc / 64; ++t) {
        const int cb = t & 1;
        if (t + 1 < Tc / 64) {
            STG_KV(t + 1, cb ^ 1);           // prefetch next tile (buffer freed by prev end-barrier)
            asm volatile("s_waitcnt vmcnt(2)\n\ts_barrier" ::: "memory");   // tile t landed
        } else {
            asm volatile("s_waitcnt vmcnt(0)\n\ts_barrier" ::: "memory");
        }
        const char* Kb = (const char*)&Ks[cb][0];
        const char* Vb = (const char*)&Vs[cb][0];

        // S^T = K Q^T (A = K rows -> m=s, B = Q rows -> n=q), then softcap+exp -> Ps[q][s]
        #pragma unroll
        for (int jh = 0; jh < 2; ++jh) {    // j-half: s-blocks {2jh, 2jh+1}
            f32x4 st[2][2] = {};
            #pragma unroll
            for (int kt = 0; kt < 2; ++kt) {
                short8 ak[2];
                #pragma unroll
                for (int jj = 0; jj < 2; ++jj)
                    ak[jj] = *(const short8*)(Kb + ((jh * 2 + jj) * 16 + l16) * 128 + (kt ? rslot1 : rslot0));
                __builtin_amdgcn_s_setprio(1);
                #pragma unroll
                for (int jj = 0; jj < 2; ++jj)
                    #pragma unroll
                    for (int i = 0; i < 2; ++i)
                        st[jj][i] = __builtin_amdgcn_mfma_f32_16x16x32_bf16(ak[jj], bq[kt][i], st[jj][i], 0, 0, 0);
                __builtin_amdgcn_s_setprio(0);
            }
            // epilogue: lane holds 4 consecutive s (quad*4+r) for q = i*16+l16
            #pragma unroll
            for (int jj = 0; jj < 2; ++jj)
                #pragma unroll
                for (int i = 0; i < 2; ++i) {
                    union { short4v v; unsigned short u[4]; } pk;
                    #pragma unroll
                    for (int r = 0; r < 4; ++r) {
                        const float sc = st[jj][i][r];
                        const float u  = sc * sc;
                        float tt = sc * fmaf(fmaf(C2, u, C1), u, C0);
                        tt = fminf(tt, 60.0f);
                        const float p = __expf(tt);
                        __hip_bfloat16 h = __float2bfloat16(p);
                        pk.u[r] = __builtin_bit_cast(unsigned short, h);
                    }
                    *(short4v*)&Psw[(i * 16 + l16) * LP + (jh * 2 + jj) * 16 + quad * 4] = pk.v;
                }
        }
        asm volatile("" ::: "memory");      // order P writes before P reads (wave-private)

        // O += P V, l += P * ones   (A = P[q][s], B = Vs[h][s])
        #pragma unroll
        for (int kt = 0; kt < 2; ++kt) {
            short8 ap[2], bv_[4];
            #pragma unroll
            for (int i = 0; i < 2; ++i)
                ap[i] = *(const short8*)&Psw[(i * 16 + l16) * LP + kt * 32 + quad * 8];
            #pragma unroll
            for (int ht = 0; ht < 4; ++ht)
                bv_[ht] = *(const short8*)(Vb + (ht * 16 + l16) * 128 + (kt ? rslot1 : rslot0));
            __builtin_amdgcn_s_setprio(1);
            #pragma unroll
            for (int i = 0; i < 2; ++i)
                l_mf[i] = __builtin_amdgcn_mfma_f32_16x16x32_bf16(ap[i], ones, l_mf[i], 0, 0, 0);
            #pragma unroll
            for (int i = 0; i < 2; ++i)
                #pragma unroll
                for (int ht = 0; ht < 4; ++ht)
                    o_acc[i][ht] = __builtin_amdgcn_mfma_f32_16x16x32_bf16(ap[i], bv_[ht], o_acc[i][ht], 0, 0, 0);
            __builtin_amdgcn_s_setprio(0);
        }
        asm volatile("s_barrier" ::: "memory");   // all waves done with buf[cb] before next DMA overwrites
    }
    #undef STG_KV

    // normalize + store (l_mf rows align with o_acc rows; no cross-lane reduce needed)
    #pragma unroll
    for (int i = 0; i < 2; ++i) {
        float linv[4];
        #pragma unroll
        for (int r = 0; r < 4; ++r) linv[r] = 1.0f / l_mf[i][r];
        #pragma unroll
        for (int ht = 0; ht < 4; ++ht)
            #pragma unroll
            for (int r = 0; r < 4; ++r) {
                const int row = t0 + wm + i * 16 + quad * 4 + r;
                const int col = hn * Hc + ht * 16 + l16;
                ctx[((size_t)(bb * Tc + row)) * Dc + col] =
                    __float2bfloat16(o_acc[i][ht][r] * linv[r]);
            }
    }
}

extern "C" void kernel_launch(void* const* d_in, const int* in_sizes, int n_in,
                              void* d_out, int out_size, void* d_ws, size_t ws_size,
                              hipStream_t stream) {
    const float* inputs = (const float*)d_in[0];
    const float* ln1_g  = (const float*)d_in[1];
    const float* ln1_b  = (const float*)d_in[2];
    const float* wq     = (const float*)d_in[3];
    const float* bq     = (const float*)d_in[4];
    const float* wk     = (const float*)d_in[5];
    const float* bk     = (const float*)d_in[6];
    const float* wv     = (const float*)d_in[7];
    const float* bv     = (const float*)d_in[8];
    const float* wo     = (const float*)d_in[9];
    const float* bo     = (const float*)d_in[10];
    const float* ln2_g  = (const float*)d_in[11];
    const float* ln2_b  = (const float*)d_in[12];
    const float* w1     = (const float*)d_in[13];
    const float* b1     = (const float*)d_in[14];
    const float* w2     = (const float*)d_in[15];
    const float* b2     = (const float*)d_in[16];

    char* ws = (char*)d_ws;
    auto alloc = [&](size_t bytes) {
        char* p = ws;
        ws += (bytes + 255) & ~(size_t)255;
        return p;
    };
    __hip_bfloat16* wqkv_t = (__hip_bfloat16*)alloc((size_t)3072 * 1024 * 2);
    __hip_bfloat16* wo_t   = (__hip_bfloat16*)alloc((size_t)1024 * 1024 * 2);
    __hip_bfloat16* w1_t   = (__hip_bfloat16*)alloc((size_t)4096 * 1024 * 2);
    __hip_bfloat16* w2_t   = (__hip_bfloat16*)alloc((size_t)4096 * 1024 * 2);
    float*          bqkv   = (float*)alloc(3072 * 4);
    __hip_bfloat16* xn     = (__hip_bfloat16*)alloc((size_t)Mrows * 1024 * 2);
    __hip_bfloat16* qkv    = (__hip_bfloat16*)alloc((size_t)Mrows * 3072 * 2);
    __hip_bfloat16* vTr    = (__hip_bfloat16*)alloc((size_t)64 * 64 * Tc * 2);
    __hip_bfloat16* ctx    = (__hip_bfloat16*)alloc((size_t)Mrows * 1024 * 2);
    float*          xres   = (float*)alloc((size_t)Mrows * 1024 * 4);
    __hip_bfloat16* y1     = qkv;   // alias: qkv dead after attention+out-proj

    dim3 blk(256);
    transpose_cvt<<<dim3(32, 32), blk, 0, stream>>>(wq, wqkv_t, 1024, 1024);
    transpose_cvt<<<dim3(32, 32), blk, 0, stream>>>(wk, wqkv_t + 1024 * 1024, 1024, 1024);
    transpose_cvt<<<dim3(32, 32), blk, 0, stream>>>(wv, wqkv_t + 2048 * 1024, 1024, 1024);
    transpose_cvt<<<dim3(32, 32), blk, 0, stream>>>(wo, wo_t, 1024, 1024);
    transpose_cvt<<<dim3(128, 32), blk, 0, stream>>>(w1, w1_t, 1024, 4096);
    transpose_cvt<<<dim3(32, 128), blk, 0, stream>>>(w2, w2_t, 4096, 1024);
    concat_bias<<<dim3(12), blk, 0, stream>>>(bq, bk, bv, bqkv);

    ln_kernel<<<dim3(Mrows), blk, 0, stream>>>(inputs, ln1_g, ln1_b, xn);
    gemm256<0, true><<<dim3(32, 12), dim3(512), 0, stream>>>(xn, wqkv_t, bqkv, nullptr, qkv, Mrows, 3072, 1024);
    transpose_v<<<dim3(64, 2, 64), blk, 0, stream>>>(qkv, vTr);
    flash_attn<<<dim3(512), dim3(512), 0, stream>>>(qkv, vTr, ctx);
    gemm256x128<2, false><<<dim3(32, 8), dim3(512), 0, stream>>>(ctx, wo_t, bo, inputs, xres, Mrows, 1024, 1024);
    ln_kernel<<<dim3(Mrows), blk, 0, stream>>>(xres, ln2_g, ln2_b, xn);
    gemm256<1, true><<<dim3(32, 16), dim3(512), 0, stream>>>(xn, w1_t, b1, nullptr, y1, Mrows, 4096, 1024);
    gemm256x128<2, false><<<dim3(32, 8), dim3(512), 0, stream>>>(y1, w2_t, b2, xres, (float*)d_out, Mrows, 1024, 4096);
}